// Round 3
// baseline (49.283 us; speedup 1.0000x reference)
//
#include <hip/hip_runtime.h>
#include <hip/hip_bf16.h>

#define MM 4096
#define NN 512
#define RR 32

__device__ __forceinline__ float softplus_f(float x) {
    return x > 20.0f ? x : log1pf(__expf(x));
}

// ---------------------------------------------------------------------------
// Kernel A: 32 independent 4096-point FFTs of softplus(H) rows.
// Radix-2 Stockham autosort (OTFFT-style DIF, natural-order output),
// convention e^{-2pi i kn/N} == numpy fft. One block per row, 1024 threads,
// double LDS buffers (2 x 32 KB = 64 KB). Result -> d_ws (32 x 4096 complex).
// ---------------------------------------------------------------------------
__global__ __launch_bounds__(1024) void fft_rows_kernel(const float* __restrict__ H,
                                                        float2* __restrict__ hft) {
    __shared__ float2 bufA[MM];
    __shared__ float2 bufB[MM];
    const int d = blockIdx.x;
    const float* Hrow = H + (size_t)d * MM;

    for (int t = threadIdx.x; t < MM; t += 1024) {
        bufA[t] = make_float2(softplus_f(Hrow[t]), 0.0f);
    }
    __syncthreads();

    float2* cur = bufA;
    float2* nxt = bufB;
    for (int i = 0; i < 12; ++i) {
        const int st  = 1 << i;        // stride s
        const int n_i = MM >> i;       // current sub-transform length
        const int m_i = n_i >> 1;
        const float inv_n = 1.0f / (float)n_i;
        for (int t = threadIdx.x; t < MM / 2; t += 1024) {
            const int p = t >> i;          // [0, m_i)
            const int q = t & (st - 1);    // [0, st)
            float2 a = cur[q + st * p];
            float2 b = cur[q + st * (p + m_i)];
            float2 sum = make_float2(a.x + b.x, a.y + b.y);
            float2 dif = make_float2(a.x - b.x, a.y - b.y);
            // wp = e^{-2*pi*i * p / n_i}; v_sin/v_cos take revolutions
            const float rev = (float)p * inv_n;   // [0, 0.5) -> in range
            const float c  = __builtin_amdgcn_cosf(rev);
            const float sn = -__builtin_amdgcn_sinf(rev);
            // out: sum -> [q + st*2p],  dif*wp -> [q + st*(2p+1)]
            nxt[q + st * (2 * p)]     = sum;
            nxt[q + st * (2 * p + 1)] = make_float2(dif.x * c - dif.y * sn,
                                                    dif.x * sn + dif.y * c);
        }
        __syncthreads();
        float2* tmp = cur; cur = nxt; nxt = tmp;
    }
    // 12 stages (even) -> natural-order result back in bufA (== cur)
    for (int t = threadIdx.x; t < MM; t += 1024) {
        hft[(size_t)d * MM + t] = cur[t];
    }
}

// ---------------------------------------------------------------------------
// Kernel B: V[n,m] = sum_d spW[n,d] * e^{-2pi i tau[n,d] m / M} * Hft[d,m]
// Block = 8 n-rows x 256 m-cols; 256 threads; thread = (n_local, m_lane),
// 8 m-values at stride 32. Hft read from global (L2-resident, 1 MB).
// CPLX=false: store Re(V) only. CPLX=true: interleaved complex.
// ---------------------------------------------------------------------------
template <bool CPLX>
__global__ __launch_bounds__(256) void shiftnmf_main(const float* __restrict__ W,
                                                     const float* __restrict__ tau,
                                                     const float2* __restrict__ hft,
                                                     float* __restrict__ out) {
    __shared__ float spw_s[8][RR];
    __shared__ float tau_s[8][RR];

    const int tid = threadIdx.x;
    const int mb  = blockIdx.x * 256;
    const int nb  = blockIdx.y * 8;

    {   // 256 threads exactly cover the 8x32 W/tau tile
        const int dd = tid & 31;
        const int nl = tid >> 5;
        spw_s[nl][dd] = softplus_f(W[(size_t)(nb + nl) * RR + dd]);
        tau_s[nl][dd] = tau[(size_t)(nb + nl) * RR + dd] * (1.0f / (float)MM);
    }
    __syncthreads();

    const int nl = tid >> 5;
    const int ml = tid & 31;

    float accR[8];
    float accI[CPLX ? 8 : 1];
#pragma unroll
    for (int k = 0; k < 8; ++k) accR[k] = 0.0f;
    if (CPLX) {
#pragma unroll
        for (int k = 0; k < 8; ++k) accI[k] = 0.0f;
    }

    const float gm0 = (float)(mb + ml);

    for (int d = 0; d < RR; ++d) {
        const float A  = spw_s[nl][d];
        const float tf = tau_s[nl][d];
        float r = tf * gm0;               // phase in revolutions, |r| < ~6
        const float step = tf * 32.0f;
        const float2* hrow = hft + (size_t)d * MM + mb + ml;
#pragma unroll
        for (int k = 0; k < 8; ++k) {
            const float2 h = hrow[32 * k];
            const float rf = r - floorf(r);          // reduce to [0,1)
            const float c = __builtin_amdgcn_cosf(rf);
            const float s = __builtin_amdgcn_sinf(rf);
            // A * (c - i s) * (h.x + i h.y)
            accR[k] = fmaf(A, fmaf(s, h.y, c * h.x), accR[k]);
            if (CPLX) accI[k] = fmaf(A, fmaf(-s, h.x, c * h.y), accI[k]);
            r += step;
        }
    }

    if (!CPLX) {
        float* orow = out + (size_t)(nb + nl) * MM + mb + ml;
#pragma unroll
        for (int k = 0; k < 8; ++k) orow[32 * k] = accR[k];
    } else {
        float2* orow = (float2*)out + (size_t)(nb + nl) * MM + mb + ml;
#pragma unroll
        for (int k = 0; k < 8; ++k) orow[32 * k] = make_float2(accR[k], accI[k]);
    }
}

extern "C" void kernel_launch(void* const* d_in, const int* in_sizes, int n_in,
                              void* d_out, int out_size, void* d_ws, size_t ws_size,
                              hipStream_t stream) {
    const float* W   = (const float*)d_in[0];   // (512, 32)
    const float* H   = (const float*)d_in[1];   // (32, 4096)
    const float* tau = (const float*)d_in[2];   // (512, 32)

    const size_t hft_bytes = (size_t)RR * MM * sizeof(float2);  // 1 MB
    if (ws_size < hft_bytes) {
        // Cannot stage the spectrum safely; bail (numeric fail, no crash).
        return;
    }
    float2* hft = (float2*)d_ws;

    fft_rows_kernel<<<RR, 1024, 0, stream>>>(H, hft);

    dim3 grid(MM / 256, NN / 8);
    if (out_size >= 2 * NN * MM) {
        // d_out holds interleaved complex64
        shiftnmf_main<true><<<grid, 256, 0, stream>>>(W, tau, hft, (float*)d_out);
    } else {
        // d_out holds Re(V) as float32 (512 x 4096)
        shiftnmf_main<false><<<grid, 256, 0, stream>>>(W, tau, hft, (float*)d_out);
    }
}

// Round 4
// 38.779 us; speedup vs baseline: 1.2709x; 1.2709x over previous
//
#include <hip/hip_runtime.h>
#include <hip/hip_bf16.h>

#define MM 4096
#define NN 512
#define RR 32

__device__ __forceinline__ float softplus_f(float x) {
    return x > 20.0f ? x : log1pf(__expf(x));
}

// ---------------------------------------------------------------------------
// Kernel A: 32 independent 4096-point FFTs of softplus(H) rows.
// Radix-2 Stockham autosort (DIF, natural-order output), e^{-2pi i kn/N}.
// One block per row, 1024 threads, double LDS buffers (2 x 32 KB).
// Result -> d_ws (32 x 4096 complex64).  [unchanged from round 3 — verified]
// ---------------------------------------------------------------------------
__global__ __launch_bounds__(1024) void fft_rows_kernel(const float* __restrict__ H,
                                                        float2* __restrict__ hft) {
    __shared__ float2 bufA[MM];
    __shared__ float2 bufB[MM];
    const int d = blockIdx.x;
    const float* Hrow = H + (size_t)d * MM;

    for (int t = threadIdx.x; t < MM; t += 1024) {
        bufA[t] = make_float2(softplus_f(Hrow[t]), 0.0f);
    }
    __syncthreads();

    float2* cur = bufA;
    float2* nxt = bufB;
    for (int i = 0; i < 12; ++i) {
        const int st  = 1 << i;
        const int n_i = MM >> i;
        const int m_i = n_i >> 1;
        const float inv_n = 1.0f / (float)n_i;
        for (int t = threadIdx.x; t < MM / 2; t += 1024) {
            const int p = t >> i;
            const int q = t & (st - 1);
            float2 a = cur[q + st * p];
            float2 b = cur[q + st * (p + m_i)];
            float2 sum = make_float2(a.x + b.x, a.y + b.y);
            float2 dif = make_float2(a.x - b.x, a.y - b.y);
            const float rev = (float)p * inv_n;     // [0, 0.5)
            const float c  = __builtin_amdgcn_cosf(rev);
            const float sn = -__builtin_amdgcn_sinf(rev);
            nxt[q + st * (2 * p)]     = sum;
            nxt[q + st * (2 * p + 1)] = make_float2(dif.x * c - dif.y * sn,
                                                    dif.x * sn + dif.y * c);
        }
        __syncthreads();
        float2* tmp = cur; cur = nxt; nxt = tmp;
    }
    for (int t = threadIdx.x; t < MM; t += 1024) {
        hft[(size_t)d * MM + t] = cur[t];
    }
}

// ---------------------------------------------------------------------------
// Kernel B: V[n,m] = sum_d spW[n,d] * e^{-2pi i tau[n,d] m / M} * Hft[d,m]
// Phasor-recurrence version:
//   per (n,d): 4 transcendentals (init + step), then rotate by 4-FMA complex
//   multiply across K=4 m-values; A folded into the initial phasor.
// Register blocking: NB=4 n-rows per thread -> each Hft load feeds 4 terms.
// Block: 256 thr = 8 groups x 32 lanes; covers 32 n-rows x 128 m-cols.
// Grid: (4096/128, 512/32) = (32, 16) = 512 blocks.
// ---------------------------------------------------------------------------
template <bool CPLX>
__global__ __launch_bounds__(256) void shiftnmf_main(const float* __restrict__ W,
                                                     const float* __restrict__ tau,
                                                     const float2* __restrict__ hft,
                                                     float* __restrict__ out) {
    __shared__ float spw_s[RR][RR];   // [n_local][d]
    __shared__ float tau_s[RR][RR];

    const int tid = threadIdx.x;
    const int mb  = blockIdx.x * 128;
    const int nb  = blockIdx.y * 32;

    for (int idx = tid; idx < RR * RR; idx += 256) {
        const int nl = idx >> 5;
        const int dd = idx & 31;
        spw_s[nl][dd] = softplus_f(W[(size_t)(nb + nl) * RR + dd]);
        tau_s[nl][dd] = tau[(size_t)(nb + nl) * RR + dd] * (1.0f / (float)MM);
    }
    __syncthreads();

    const int g  = tid >> 5;     // 0..7
    const int ml = tid & 31;
    const int n0 = g * 4;        // local base row for this thread

    float accR[4][4], accI[4][4];
#pragma unroll
    for (int j = 0; j < 4; ++j)
#pragma unroll
        for (int k = 0; k < 4; ++k) { accR[j][k] = 0.0f; if (CPLX) accI[j][k] = 0.0f; }

    const float m0f = (float)(mb + ml);
    const float2* hcol = hft + mb + ml;

    // prefetch d=0
    float2 hc0 = hcol[0];
    float2 hc1 = hcol[32];
    float2 hc2 = hcol[64];
    float2 hc3 = hcol[96];

    for (int d = 0; d < RR; ++d) {
        // prefetch d+1
        float2 hn0, hn1, hn2, hn3;
        if (d + 1 < RR) {
            const float2* hnxt = hcol + (size_t)(d + 1) * MM;
            hn0 = hnxt[0]; hn1 = hnxt[32]; hn2 = hnxt[64]; hn3 = hnxt[96];
        }
        const float2 hh0 = hc0, hh1 = hc1, hh2 = hc2, hh3 = hc3;

#pragma unroll
        for (int j = 0; j < 4; ++j) {
            const float A  = spw_s[n0 + j][d];
            const float tf = tau_s[n0 + j][d];
            float r0 = tf * m0f;
            r0 -= floorf(r0);                       // [0,1) for v_sin/v_cos
            const float c0 = __builtin_amdgcn_cosf(r0);
            const float s0 = __builtin_amdgcn_sinf(r0);
            float cr = A * c0;                      // A * cos(phase)
            float ci = A * s0;                      // A * sin(phase)
            float dl = tf * 32.0f;                  // step: 32 m per k
            dl -= floorf(dl);
            const float Cd = __builtin_amdgcn_cosf(dl);
            const float Sd = __builtin_amdgcn_sinf(dl);

            // k = 0..3: acc then rotate phasor by the step
            // Re += cr*hx + ci*hy ; Im += cr*hy - ci*hx   (e^{-i phi} convention)
#define STEP(k, HH)                                                         \
            accR[j][k] = fmaf(cr, HH.x, fmaf(ci, HH.y, accR[j][k]));        \
            if (CPLX) accI[j][k] = fmaf(cr, HH.y, fmaf(-ci, HH.x, accI[j][k])); \
            { const float crn = fmaf(cr, Cd, -(ci * Sd));                   \
              const float cin = fmaf(ci, Cd,  (cr * Sd));                   \
              cr = crn; ci = cin; }
            STEP(0, hh0)
            STEP(1, hh1)
            STEP(2, hh2)
            STEP(3, hh3)
#undef STEP
        }
        hc0 = hn0; hc1 = hn1; hc2 = hn2; hc3 = hn3;
    }

    if (!CPLX) {
#pragma unroll
        for (int j = 0; j < 4; ++j) {
            float* orow = out + (size_t)(nb + n0 + j) * MM + mb + ml;
#pragma unroll
            for (int k = 0; k < 4; ++k) orow[32 * k] = accR[j][k];
        }
    } else {
#pragma unroll
        for (int j = 0; j < 4; ++j) {
            float2* orow = (float2*)out + (size_t)(nb + n0 + j) * MM + mb + ml;
#pragma unroll
            for (int k = 0; k < 4; ++k) orow[32 * k] = make_float2(accR[j][k], accI[j][k]);
        }
    }
}

extern "C" void kernel_launch(void* const* d_in, const int* in_sizes, int n_in,
                              void* d_out, int out_size, void* d_ws, size_t ws_size,
                              hipStream_t stream) {
    const float* W   = (const float*)d_in[0];   // (512, 32)
    const float* H   = (const float*)d_in[1];   // (32, 4096)
    const float* tau = (const float*)d_in[2];   // (512, 32)

    const size_t hft_bytes = (size_t)RR * MM * sizeof(float2);  // 1 MB
    if (ws_size < hft_bytes) return;            // safe bail (no crash)
    float2* hft = (float2*)d_ws;

    fft_rows_kernel<<<RR, 1024, 0, stream>>>(H, hft);

    dim3 grid(MM / 128, NN / 32);
    if (out_size >= 2 * NN * MM) {
        shiftnmf_main<true><<<grid, 256, 0, stream>>>(W, tau, hft, (float*)d_out);
    } else {
        shiftnmf_main<false><<<grid, 256, 0, stream>>>(W, tau, hft, (float*)d_out);
    }
}

// Round 5
// 33.565 us; speedup vs baseline: 1.4683x; 1.1553x over previous
//
#include <hip/hip_runtime.h>
#include <hip/hip_bf16.h>

#define MM 4096
#define NN 512
#define RR 32

__device__ __forceinline__ float softplus_f(float x) {
    return x > 20.0f ? x : log1pf(__expf(x));
}

// ---------------------------------------------------------------------------
// Kernel A: 32 independent 4096-point FFTs of softplus(H) rows.
// Radix-4 Stockham autosort DIF (6 stages), convention e^{-2pi i kn/N}.
// One block per row, 1024 threads = one radix-4 butterfly per thread/stage.
// Ping-pong between halves of ONE shared array with compile-time stage
// unrolling (address space statically LDS; no pointer-phi).
// Twiddles: 2 trans per butterfly; w^2, w^3 via double-angle / angle-add.
// ---------------------------------------------------------------------------
__global__ __launch_bounds__(1024) void fft_rows_kernel(const float* __restrict__ H,
                                                        float2* __restrict__ hft) {
    __shared__ float2 buf[2][MM];   // 64 KB
    const int d   = blockIdx.x;
    const int tid = threadIdx.x;
    const float* Hrow = H + (size_t)d * MM;

    for (int t = tid; t < MM; t += 1024)
        buf[0][t] = make_float2(softplus_f(Hrow[t]), 0.0f);
    __syncthreads();

#pragma unroll
    for (int i = 0; i < 6; ++i) {
        const int   sh    = 2 * i;
        const int   st    = 1 << sh;                   // 4^i
        const float inv_n = 1.0f / (float)(MM >> sh);  // 1 / n_i
        const float2* cur = buf[i & 1];
        float2*       nxt = buf[(i & 1) ^ 1];

        const int t = tid;                 // exactly 1024 butterflies
        const int p = t >> sh;
        const int q = t & (st - 1);

        const float2 a0 = cur[t];
        const float2 a1 = cur[t + 1024];
        const float2 a2 = cur[t + 2048];
        const float2 a3 = cur[t + 3072];

        // DFT-4 with omega = -i
        const float e0x = a0.x + a2.x, e0y = a0.y + a2.y;
        const float e1x = a1.x + a3.x, e1y = a1.y + a3.y;
        const float o0x = a0.x - a2.x, o0y = a0.y - a2.y;
        const float o1x = a1.x - a3.x, o1y = a1.y - a3.y;

        const float2 y0 = make_float2(e0x + e1x, e0y + e1y);
        const float2 y2 = make_float2(e0x - e1x, e0y - e1y);
        const float2 y1 = make_float2(o0x + o1y, o0y - o1x);   // o0 - i*o1
        const float2 y3 = make_float2(o0x - o1y, o0y + o1x);   // o0 + i*o1

        // w_r = e^{-2 pi i r p / n_i}; v_sin/v_cos take revolutions
        const float th = (float)p * inv_n;                     // [0, 0.25)
        const float c1 = __builtin_amdgcn_cosf(th);
        const float s1 = __builtin_amdgcn_sinf(th);
        const float c2 = fmaf(-2.0f * s1, s1, 1.0f);           // cos(2a)
        const float s2 = 2.0f * s1 * c1;                       // sin(2a)
        const float c3 = c1 * c2 - s1 * s2;                    // cos(3a)
        const float s3 = s1 * c2 + c1 * s2;                    // sin(3a)

        // z_r = y_r * (c_r, -s_r)
        const int base = 4 * t - 3 * q;        // q + st*4p
        nxt[base]          = y0;
        nxt[base + st]     = make_float2(fmaf(y1.x, c1,  y1.y * s1),
                                         fmaf(y1.y, c1, -y1.x * s1));
        nxt[base + 2*st]   = make_float2(fmaf(y2.x, c2,  y2.y * s2),
                                         fmaf(y2.y, c2, -y2.x * s2));
        nxt[base + 3*st]   = make_float2(fmaf(y3.x, c3,  y3.y * s3),
                                         fmaf(y3.y, c3, -y3.x * s3));
        __syncthreads();
    }

    // 6 stages (even) -> natural-order result in buf[0]
    for (int t = tid; t < MM; t += 1024)
        hft[(size_t)d * MM + t] = buf[0][t];
}

// ---------------------------------------------------------------------------
// Kernel B: V[n,m] = sum_d spW[n,d] * e^{-2pi i tau[n,d] m / M} * Hft[d,m]
// Dual-phasor recurrence, K=8 m-values per phasor-init (trans/term = 0.5):
//   phasor a covers k=0,2,4,6; phasor b (= a advanced by delta) covers odd k;
//   both step by 2*delta via double-angle (no extra trans).
// Block 256 thr = 8 groups x 32 lanes; NB=2 rows/group -> 16 rows x 256 m.
// Grid (4096/256, 512/16) = (16, 32) = 512 blocks (2/CU).
// ---------------------------------------------------------------------------
template <bool CPLX>
__global__ __launch_bounds__(256) void shiftnmf_main(const float* __restrict__ W,
                                                     const float* __restrict__ tau,
                                                     const float2* __restrict__ hft,
                                                     float* __restrict__ out) {
    __shared__ float spw_s[16][RR];
    __shared__ float tau_s[16][RR];

    const int tid = threadIdx.x;
    const int mb  = blockIdx.x * 256;
    const int nb  = blockIdx.y * 16;

    for (int idx = tid; idx < 16 * RR; idx += 256) {
        const int nl = idx >> 5;
        const int dd = idx & 31;
        spw_s[nl][dd] = softplus_f(W[(size_t)(nb + nl) * RR + dd]);
        tau_s[nl][dd] = tau[(size_t)(nb + nl) * RR + dd] * (1.0f / (float)MM);
    }
    __syncthreads();

    const int g  = tid >> 5;        // 0..7
    const int ml = tid & 31;
    const int n0 = g * 2;           // 2 rows per group
    const float m0f = (float)(mb + ml);
    const float2* hcol = hft + mb + ml;

    float accR[2][8];
    float accI[2][CPLX ? 8 : 1];
#pragma unroll
    for (int j = 0; j < 2; ++j)
#pragma unroll
        for (int k = 0; k < 8; ++k) {
            accR[j][k] = 0.0f;
            if (CPLX) accI[j][k] = 0.0f;
        }

    float2 hc[8], hn[8];
#pragma unroll
    for (int k = 0; k < 8; ++k) hc[k] = hcol[32 * k];

    for (int d = 0; d < RR; ++d) {
        // prefetch next d (clamped; d=31's prefetch is unused)
        const float2* hnp = hcol + (size_t)((d + 1 < RR) ? d + 1 : d) * MM;
#pragma unroll
        for (int k = 0; k < 8; ++k) hn[k] = hnp[32 * k];

#pragma unroll
        for (int j = 0; j < 2; ++j) {
            const float A  = spw_s[n0 + j][d];
            const float tf = tau_s[n0 + j][d];
            float r0 = tf * m0f;  r0 -= floorf(r0);       // [0,1)
            float dl = tf * 32.0f; dl -= floorf(dl);      // [0,1)
            const float c0 = __builtin_amdgcn_cosf(r0);
            const float s0 = __builtin_amdgcn_sinf(r0);
            const float cd = __builtin_amdgcn_cosf(dl);
            const float sd = __builtin_amdgcn_sinf(dl);
            float ca = A * c0, sa = A * s0;               // phasor a (k even)
            float cb = ca * cd - sa * sd;                 // phasor b (k odd)
            float sb = sa * cd + ca * sd;
            const float c2 = fmaf(-2.0f * sd, sd, 1.0f);  // step = 2*delta
            const float s2 = 2.0f * sd * cd;

#pragma unroll
            for (int t4 = 0; t4 < 4; ++t4) {
                const float2 h0 = hc[2 * t4];
                const float2 h1 = hc[2 * t4 + 1];
                // A * e^{-i phi} * h: Re += c*hx + s*hy ; Im += c*hy - s*hx
                accR[j][2*t4]   = fmaf(ca, h0.x, fmaf(sa, h0.y, accR[j][2*t4]));
                accR[j][2*t4+1] = fmaf(cb, h1.x, fmaf(sb, h1.y, accR[j][2*t4+1]));
                if (CPLX) {
                    accI[j][2*t4]   = fmaf(ca, h0.y, fmaf(-sa, h0.x, accI[j][2*t4]));
                    accI[j][2*t4+1] = fmaf(cb, h1.y, fmaf(-sb, h1.x, accI[j][2*t4+1]));
                }
                if (t4 < 3) {
                    const float can = fmaf(ca, c2, -(sa * s2));
                    const float san = fmaf(sa, c2,  (ca * s2));
                    const float cbn = fmaf(cb, c2, -(sb * s2));
                    const float sbn = fmaf(sb, c2,  (cb * s2));
                    ca = can; sa = san; cb = cbn; sb = sbn;
                }
            }
        }
#pragma unroll
        for (int k = 0; k < 8; ++k) hc[k] = hn[k];
    }

#pragma unroll
    for (int j = 0; j < 2; ++j) {
        if (!CPLX) {
            float* orow = out + (size_t)(nb + n0 + j) * MM + mb + ml;
#pragma unroll
            for (int k = 0; k < 8; ++k) orow[32 * k] = accR[j][k];
        } else {
            float2* orow = (float2*)out + (size_t)(nb + n0 + j) * MM + mb + ml;
#pragma unroll
            for (int k = 0; k < 8; ++k)
                orow[32 * k] = make_float2(accR[j][k], accI[j][k]);
        }
    }
}

extern "C" void kernel_launch(void* const* d_in, const int* in_sizes, int n_in,
                              void* d_out, int out_size, void* d_ws, size_t ws_size,
                              hipStream_t stream) {
    const float* W   = (const float*)d_in[0];   // (512, 32)
    const float* H   = (const float*)d_in[1];   // (32, 4096)
    const float* tau = (const float*)d_in[2];   // (512, 32)

    const size_t hft_bytes = (size_t)RR * MM * sizeof(float2);  // 1 MB
    if (ws_size < hft_bytes) return;            // safe bail (no crash)
    float2* hft = (float2*)d_ws;

    fft_rows_kernel<<<RR, 1024, 0, stream>>>(H, hft);

    dim3 grid(MM / 256, NN / 16);
    if (out_size >= 2 * NN * MM) {
        shiftnmf_main<true><<<grid, 256, 0, stream>>>(W, tau, hft, (float*)d_out);
    } else {
        shiftnmf_main<false><<<grid, 256, 0, stream>>>(W, tau, hft, (float*)d_out);
    }
}

// Round 6
// 30.942 us; speedup vs baseline: 1.5928x; 1.0848x over previous
//
#include <hip/hip_runtime.h>
#include <hip/hip_bf16.h>

#define MM 4096
#define NN 512
#define RR 32

__device__ __forceinline__ float softplus_f(float x) {
    return x > 20.0f ? x : log1pf(__expf(x));
}

// ---------------------------------------------------------------------------
// Kernel A: 32 independent 4096-point FFTs of softplus(H) rows.
// Radix-4 Stockham autosort DIF (6 stages), e^{-2pi i kn/N}. Unchanged from
// round 5 (verified).
// ---------------------------------------------------------------------------
__global__ __launch_bounds__(1024) void fft_rows_kernel(const float* __restrict__ H,
                                                        float2* __restrict__ hft) {
    __shared__ float2 buf[2][MM];   // 64 KB
    const int d   = blockIdx.x;
    const int tid = threadIdx.x;
    const float* Hrow = H + (size_t)d * MM;

    for (int t = tid; t < MM; t += 1024)
        buf[0][t] = make_float2(softplus_f(Hrow[t]), 0.0f);
    __syncthreads();

#pragma unroll
    for (int i = 0; i < 6; ++i) {
        const int   sh    = 2 * i;
        const int   st    = 1 << sh;                   // 4^i
        const float inv_n = 1.0f / (float)(MM >> sh);  // 1 / n_i
        const float2* cur = buf[i & 1];
        float2*       nxt = buf[(i & 1) ^ 1];

        const int t = tid;
        const int p = t >> sh;
        const int q = t & (st - 1);

        const float2 a0 = cur[t];
        const float2 a1 = cur[t + 1024];
        const float2 a2 = cur[t + 2048];
        const float2 a3 = cur[t + 3072];

        const float e0x = a0.x + a2.x, e0y = a0.y + a2.y;
        const float e1x = a1.x + a3.x, e1y = a1.y + a3.y;
        const float o0x = a0.x - a2.x, o0y = a0.y - a2.y;
        const float o1x = a1.x - a3.x, o1y = a1.y - a3.y;

        const float2 y0 = make_float2(e0x + e1x, e0y + e1y);
        const float2 y2 = make_float2(e0x - e1x, e0y - e1y);
        const float2 y1 = make_float2(o0x + o1y, o0y - o1x);   // o0 - i*o1
        const float2 y3 = make_float2(o0x - o1y, o0y + o1x);   // o0 + i*o1

        const float th = (float)p * inv_n;                     // [0, 0.25)
        const float c1 = __builtin_amdgcn_cosf(th);
        const float s1 = __builtin_amdgcn_sinf(th);
        const float c2 = fmaf(-2.0f * s1, s1, 1.0f);
        const float s2 = 2.0f * s1 * c1;
        const float c3 = c1 * c2 - s1 * s2;
        const float s3 = s1 * c2 + c1 * s2;

        const int base = 4 * t - 3 * q;        // q + st*4p
        nxt[base]          = y0;
        nxt[base + st]     = make_float2(fmaf(y1.x, c1,  y1.y * s1),
                                         fmaf(y1.y, c1, -y1.x * s1));
        nxt[base + 2*st]   = make_float2(fmaf(y2.x, c2,  y2.y * s2),
                                         fmaf(y2.y, c2, -y2.x * s2));
        nxt[base + 3*st]   = make_float2(fmaf(y3.x, c3,  y3.y * s3),
                                         fmaf(y3.y, c3, -y3.x * s3));
        __syncthreads();
    }

    for (int t = tid; t < MM; t += 1024)
        hft[(size_t)d * MM + t] = buf[0][t];
}

// ---------------------------------------------------------------------------
// Kernel B (real output, Hermitian-pair): iterate only m in [0, 2048).
// z = A e^{-i 2pi tf m} Hft[d,m]  ->  Re V[n,m]      += Re z
//                                     Re V[n,4096-m] += Reu*Rez + Imu*Imz
// with u = e^{-2pi i tau} per (n,d), precomputed in LDS.
// m=0 pair suppressed; m=2048 (real Nyquist bin) done by bx==0, ml==0 lanes.
// Block: 256 thr = 8 rows x 32 lanes, K=8 m per thread (stride 32).
// Grid (2048/256, 512/8) = (8, 64) = 512 blocks (2/CU).
// ---------------------------------------------------------------------------
__global__ __launch_bounds__(256) void shiftnmf_real(const float* __restrict__ W,
                                                     const float* __restrict__ tau,
                                                     const float2* __restrict__ hft,
                                                     float* __restrict__ out) {
    __shared__ float spw_s[8][RR];
    __shared__ float tf_s[8][RR];
    __shared__ float cu_s[8][RR];
    __shared__ float su_s[8][RR];
    __shared__ float h2048_s[RR];

    const int tid = threadIdx.x;
    const int mb  = blockIdx.x * 256;      // [0, 2048)
    const int nb  = blockIdx.y * 8;

    {
        const int nl = tid >> 5;
        const int dd = tid & 31;
        const float w = W[(size_t)(nb + nl) * RR + dd];
        const float t = tau[(size_t)(nb + nl) * RR + dd];
        spw_s[nl][dd] = softplus_f(w);
        tf_s[nl][dd]  = t * (1.0f / (float)MM);
        const float fr = t - floorf(t);                // frac(tau) in [0,1)
        cu_s[nl][dd] =  __builtin_amdgcn_cosf(fr);     // Re e^{-2pi i tau}
        su_s[nl][dd] = -__builtin_amdgcn_sinf(fr);     // Im e^{-2pi i tau}
    }
    if (tid < RR) h2048_s[tid] = hft[(size_t)tid * MM + 2048].x;
    __syncthreads();

    const int g  = tid >> 5;
    const int ml = tid & 31;
    const int n  = nb + g;
    const float m0f = (float)(mb + ml);
    const float2* hcol = hft + mb + ml;

    float accm[8], accp[8];
#pragma unroll
    for (int k = 0; k < 8; ++k) { accm[k] = 0.0f; accp[k] = 0.0f; }

    float2 hc[8], hn[8];
#pragma unroll
    for (int k = 0; k < 8; ++k) hc[k] = hcol[32 * k];

    for (int d = 0; d < RR; ++d) {
        const float2* hnp = hcol + (size_t)((d + 1 < RR) ? d + 1 : d) * MM;
#pragma unroll
        for (int k = 0; k < 8; ++k) hn[k] = hnp[32 * k];

        const float A  = spw_s[g][d];
        const float tf = tf_s[g][d];
        const float ru = cu_s[g][d];
        const float iu = su_s[g][d];

        float r0 = tf * m0f;   r0 -= floorf(r0);
        float dl = tf * 32.0f; dl -= floorf(dl);
        const float c0 = __builtin_amdgcn_cosf(r0);
        const float s0 = __builtin_amdgcn_sinf(r0);
        const float cd = __builtin_amdgcn_cosf(dl);
        const float sd = __builtin_amdgcn_sinf(dl);
        float ca = A * c0, sa = A * s0;               // phasor for even k
        float cb = ca * cd - sa * sd;                 // phasor for odd k
        float sb = sa * cd + ca * sd;
        const float c2 = fmaf(-2.0f * sd, sd, 1.0f);  // rotate by 2*delta
        const float s2 = 2.0f * sd * cd;

#pragma unroll
        for (int t = 0; t < 4; ++t) {
            const float2 h0 = hc[2 * t];
            const float2 h1 = hc[2 * t + 1];
            // z = (ca, sa) applied to h:  Rez = ca*hx + sa*hy, Imz = ca*hy - sa*hx
            const float rz0 = fmaf(ca, h0.x,   sa * h0.y);
            const float iz0 = fmaf(ca, h0.y, -(sa * h0.x));
            accm[2 * t]     += rz0;
            accp[2 * t]      = fmaf(ru, rz0, fmaf(iu, iz0, accp[2 * t]));
            const float rz1 = fmaf(cb, h1.x,   sb * h1.y);
            const float iz1 = fmaf(cb, h1.y, -(sb * h1.x));
            accm[2 * t + 1] += rz1;
            accp[2 * t + 1]  = fmaf(ru, rz1, fmaf(iu, iz1, accp[2 * t + 1]));
            if (t < 3) {
                const float can = fmaf(ca, c2, -(sa * s2));
                const float san = fmaf(sa, c2,  (ca * s2));
                const float cbn = fmaf(cb, c2, -(sb * s2));
                const float sbn = fmaf(sb, c2,  (cb * s2));
                ca = can; sa = san; cb = cbn; sb = sbn;
            }
        }
#pragma unroll
        for (int k = 0; k < 8; ++k) hc[k] = hn[k];
    }

    float* orow = out + (size_t)n * MM;
#pragma unroll
    for (int k = 0; k < 8; ++k) {
        const int m = mb + ml + 32 * k;       // [0, 2047]
        orow[m] = accm[k];
        if (m != 0) orow[MM - m] = accp[k];   // [2049, 4095]
    }

    // Nyquist column m = 2048: Hft[d,2048] is real; one thread per row.
    if (blockIdx.x == 0 && ml == 0) {
        float acc = 0.0f;
        for (int d = 0; d < RR; ++d) {
            float r = tf_s[g][d] * 2048.0f;
            r -= floorf(r);
            acc = fmaf(spw_s[g][d] * h2048_s[d], __builtin_amdgcn_cosf(r), acc);
        }
        orow[2048] = acc;
    }
}

// ---------------------------------------------------------------------------
// Kernel B' (complex output hedge) — round-5 kernel, unchanged (proven).
// ---------------------------------------------------------------------------
__global__ __launch_bounds__(256) void shiftnmf_cplx(const float* __restrict__ W,
                                                     const float* __restrict__ tau,
                                                     const float2* __restrict__ hft,
                                                     float* __restrict__ out) {
    __shared__ float spw_s[16][RR];
    __shared__ float tau_s[16][RR];

    const int tid = threadIdx.x;
    const int mb  = blockIdx.x * 256;
    const int nb  = blockIdx.y * 16;

    for (int idx = tid; idx < 16 * RR; idx += 256) {
        const int nl = idx >> 5;
        const int dd = idx & 31;
        spw_s[nl][dd] = softplus_f(W[(size_t)(nb + nl) * RR + dd]);
        tau_s[nl][dd] = tau[(size_t)(nb + nl) * RR + dd] * (1.0f / (float)MM);
    }
    __syncthreads();

    const int g  = tid >> 5;
    const int ml = tid & 31;
    const int n0 = g * 2;
    const float m0f = (float)(mb + ml);
    const float2* hcol = hft + mb + ml;

    float accR[2][8], accI[2][8];
#pragma unroll
    for (int j = 0; j < 2; ++j)
#pragma unroll
        for (int k = 0; k < 8; ++k) { accR[j][k] = 0.0f; accI[j][k] = 0.0f; }

    float2 hc[8], hn[8];
#pragma unroll
    for (int k = 0; k < 8; ++k) hc[k] = hcol[32 * k];

    for (int d = 0; d < RR; ++d) {
        const float2* hnp = hcol + (size_t)((d + 1 < RR) ? d + 1 : d) * MM;
#pragma unroll
        for (int k = 0; k < 8; ++k) hn[k] = hnp[32 * k];

#pragma unroll
        for (int j = 0; j < 2; ++j) {
            const float A  = spw_s[n0 + j][d];
            const float tf = tau_s[n0 + j][d];
            float r0 = tf * m0f;  r0 -= floorf(r0);
            float dl = tf * 32.0f; dl -= floorf(dl);
            const float c0 = __builtin_amdgcn_cosf(r0);
            const float s0 = __builtin_amdgcn_sinf(r0);
            const float cd = __builtin_amdgcn_cosf(dl);
            const float sd = __builtin_amdgcn_sinf(dl);
            float ca = A * c0, sa = A * s0;
            float cb = ca * cd - sa * sd;
            float sb = sa * cd + ca * sd;
            const float c2 = fmaf(-2.0f * sd, sd, 1.0f);
            const float s2 = 2.0f * sd * cd;

#pragma unroll
            for (int t4 = 0; t4 < 4; ++t4) {
                const float2 h0 = hc[2 * t4];
                const float2 h1 = hc[2 * t4 + 1];
                accR[j][2*t4]   = fmaf(ca, h0.x, fmaf(sa, h0.y, accR[j][2*t4]));
                accR[j][2*t4+1] = fmaf(cb, h1.x, fmaf(sb, h1.y, accR[j][2*t4+1]));
                accI[j][2*t4]   = fmaf(ca, h0.y, fmaf(-sa, h0.x, accI[j][2*t4]));
                accI[j][2*t4+1] = fmaf(cb, h1.y, fmaf(-sb, h1.x, accI[j][2*t4+1]));
                if (t4 < 3) {
                    const float can = fmaf(ca, c2, -(sa * s2));
                    const float san = fmaf(sa, c2,  (ca * s2));
                    const float cbn = fmaf(cb, c2, -(sb * s2));
                    const float sbn = fmaf(sb, c2,  (cb * s2));
                    ca = can; sa = san; cb = cbn; sb = sbn;
                }
            }
        }
#pragma unroll
        for (int k = 0; k < 8; ++k) hc[k] = hn[k];
    }

#pragma unroll
    for (int j = 0; j < 2; ++j) {
        float2* orow = (float2*)out + (size_t)(nb + n0 + j) * MM + mb + ml;
#pragma unroll
        for (int k = 0; k < 8; ++k)
            orow[32 * k] = make_float2(accR[j][k], accI[j][k]);
    }
}

extern "C" void kernel_launch(void* const* d_in, const int* in_sizes, int n_in,
                              void* d_out, int out_size, void* d_ws, size_t ws_size,
                              hipStream_t stream) {
    const float* W   = (const float*)d_in[0];   // (512, 32)
    const float* H   = (const float*)d_in[1];   // (32, 4096)
    const float* tau = (const float*)d_in[2];   // (512, 32)

    const size_t hft_bytes = (size_t)RR * MM * sizeof(float2);  // 1 MB
    if (ws_size < hft_bytes) return;            // safe bail (no crash)
    float2* hft = (float2*)d_ws;

    fft_rows_kernel<<<RR, 1024, 0, stream>>>(H, hft);

    if (out_size >= 2 * NN * MM) {
        dim3 grid(MM / 256, NN / 16);
        shiftnmf_cplx<<<grid, 256, 0, stream>>>(W, tau, hft, (float*)d_out);
    } else {
        dim3 grid(2048 / 256, NN / 8);
        shiftnmf_real<<<grid, 256, 0, stream>>>(W, tau, hft, (float*)d_out);
    }
}